// Round 10
// baseline (186.676 us; speedup 1.0000x reference)
//
#include <hip/hip_runtime.h>
#include <hip/hip_bf16.h>
#include <math.h>

#define Bb 8
#define Tt 512
#define Cc 512
#define Hh 8
#define HKV 4
#define Dd 64

typedef __attribute__((ext_vector_type(8))) short short8;
typedef __attribute__((ext_vector_type(4))) float float4v;
typedef __attribute__((ext_vector_type(2))) __fp16 h2;  // matches cvt_pkrtz return type

__device__ __forceinline__ h2 u2h(unsigned u) {
  union { unsigned u; h2 h; } x; x.u = u; return x.h;
}
__device__ __forceinline__ unsigned h2u(h2 h) {
  union { h2 h; unsigned u; } x; x.h = h; return x.u;
}
__device__ __forceinline__ float fdot2(h2 a, h2 b, float c) {
#if __has_builtin(__builtin_amdgcn_fdot2)
  return __builtin_amdgcn_fdot2(a, b, c, false);
#else
  return fmaf((float)a.x, (float)b.x, fmaf((float)a.y, (float)b.y, c));
#endif
}

__device__ __forceinline__ float wave_reduce_sum(float v) {
#pragma unroll
  for (int off = 32; off > 0; off >>= 1) v += __shfl_xor(v, off, 64);
  return v;
}
__device__ __forceinline__ unsigned pack_bf2(float a, float b) {
  __hip_bfloat162 h = __float22bfloat162_rn(make_float2(a, b));
  return *(unsigned*)&h;
}

// ---------------- x fp32 -> bf16 ----------------
__global__ __launch_bounds__(256) void conv_x(const float* __restrict__ x,
                                              unsigned short* __restrict__ xb) {
  int i = (blockIdx.x * 256 + threadIdx.x) * 8;
  float4 f0 = *(const float4*)&x[i];
  float4 f1 = *(const float4*)&x[i + 4];
  unsigned u[4] = {pack_bf2(f0.x, f0.y), pack_bf2(f0.z, f0.w),
                   pack_bf2(f1.x, f1.y), pack_bf2(f1.z, f1.w)};
  *(uint4*)&xb[i] = *(uint4*)u;
}

// ---------------- W transpose+convert: Wt[n][k] bf16 ----------------
__global__ __launch_bounds__(256) void conv_w(
    const float* __restrict__ Wq, const float* __restrict__ Wk,
    const float* __restrict__ Wv, const float* __restrict__ Wp,
    unsigned short* __restrict__ Wtq, unsigned short* __restrict__ Wtp) {
  __shared__ float Ts[64][65];
  const int k0 = blockIdx.x * 64;
  const int n0 = blockIdx.y * 64;
  const float* src; int ld, nc0; unsigned short* dst; int ndst;
  if (n0 < 512)       { src = Wq; ld = 512; nc0 = n0;        dst = Wtq; ndst = n0; }
  else if (n0 < 768)  { src = Wk; ld = 256; nc0 = n0 - 512;  dst = Wtq; ndst = n0; }
  else if (n0 < 1024) { src = Wv; ld = 256; nc0 = n0 - 768;  dst = Wtq; ndst = n0; }
  else                { src = Wp; ld = 512; nc0 = n0 - 1024; dst = Wtp; ndst = n0 - 1024; }
  const int t = threadIdx.x;
  const int r = t >> 4, c4 = (t & 15) << 2;
#pragma unroll
  for (int rr = 0; rr < 4; ++rr) {
    int row = (rr << 4) + r;
    float4 f = *(const float4*)&src[(k0 + row) * ld + nc0 + c4];
    Ts[row][c4] = f.x; Ts[row][c4 + 1] = f.y;
    Ts[row][c4 + 2] = f.z; Ts[row][c4 + 3] = f.w;
  }
  __syncthreads();
#pragma unroll
  for (int rr = 0; rr < 4; ++rr) {
    int nr = (rr << 4) + r;
    unsigned u0 = pack_bf2(Ts[c4][nr], Ts[c4 + 1][nr]);
    unsigned u1 = pack_bf2(Ts[c4 + 2][nr], Ts[c4 + 3][nr]);
    *(uint2*)&dst[(ndst + nr) * 512 + k0 + c4] = make_uint2(u0, u1);
  }
}

// ---------------- QKV MFMA GEMM v2: 128x128 tile (m93 structure) ----------------
// grid (32, 8), 4 waves; wave w owns 64x64 quadrant (mw=(w>>1)*64, nw=(w&1)*64),
// acc[4][4]; per K-iter 32 MFMAs vs 16 ds_read_b128 (4x density of 64x64 tile).
// Wave's 64-col span = exactly one head -> fused RMS-norm / v-pairing epilogue.
__global__ __launch_bounds__(256) void qkv_mfma(
    const unsigned short* __restrict__ xb, const unsigned short* __restrict__ Wt,
    unsigned short* __restrict__ qh, unsigned short* __restrict__ kh,
    unsigned* __restrict__ vhu) {
  __shared__ unsigned short As[128][64];
  __shared__ unsigned short Bs[128][64];
  const int m0 = blockIdx.x * 128;
  const int n0 = blockIdx.y * 128;
  const int t = threadIdx.x;
  const int w = t >> 6, lane = t & 63;
  const int mw = (w >> 1) << 6;
  const int nw = (w & 1) << 6;
  const int srow = t >> 1, scol = (t & 1) << 5;  // 2 thr/row, 32 bf16 each
  float4v acc[4][4];
#pragma unroll
  for (int mi = 0; mi < 4; ++mi)
#pragma unroll
    for (int ni = 0; ni < 4; ++ni) acc[mi][ni] = (float4v){0, 0, 0, 0};

  for (int k0 = 0; k0 < 512; k0 += 64) {
    uint4 a[4], b[4];
    const uint4* ap = (const uint4*)&xb[(m0 + srow) * 512 + k0 + scol];
    const uint4* bp = (const uint4*)&Wt[(n0 + srow) * 512 + k0 + scol];
#pragma unroll
    for (int c = 0; c < 4; ++c) { a[c] = ap[c]; b[c] = bp[c]; }
    __syncthreads();
#pragma unroll
    for (int c = 0; c < 4; ++c) {
      ((uint4*)&As[srow][scol])[c] = a[c];
      ((uint4*)&Bs[srow][scol])[c] = b[c];
    }
    __syncthreads();
    const int lm = lane & 15;
    const int kq = (lane >> 4) << 3;
#pragma unroll
    for (int kh2 = 0; kh2 < 2; ++kh2) {
      short8 aF[4], bF[4];
#pragma unroll
      for (int mi = 0; mi < 4; ++mi)
        aF[mi] = *(short8*)&As[mw + mi * 16 + lm][kq + kh2 * 32];
#pragma unroll
      for (int ni = 0; ni < 4; ++ni)
        bF[ni] = *(short8*)&Bs[nw + ni * 16 + lm][kq + kh2 * 32];
#pragma unroll
      for (int mi = 0; mi < 4; ++mi)
#pragma unroll
        for (int ni = 0; ni < 4; ++ni)
          acc[mi][ni] = __builtin_amdgcn_mfma_f32_16x16x32_bf16(
              aF[mi], bF[ni], acc[mi][ni], 0, 0, 0);
    }
  }

  const int ncol = n0 + nw;        // head-aligned (0,64,...,960)
  const int lane15 = lane & 15;
  if (ncol < 768) {
    // q or k head: fused RMS-norm over the 64-wide head (= wave's n-span)
#pragma unroll
    for (int mi = 0; mi < 4; ++mi) {
      const int rowb = m0 + mw + mi * 16 + ((lane >> 4) << 2);
#pragma unroll
      for (int r = 0; r < 4; ++r) {
        float ss = 0.0f;
#pragma unroll
        for (int ni = 0; ni < 4; ++ni)
          ss = fmaf(acc[mi][ni][r], acc[mi][ni][r], ss);
#pragma unroll
        for (int off = 1; off < 16; off <<= 1) ss += __shfl_xor(ss, off, 64);
        float sc2 = 8.0f * rsqrtf(ss + 1e-6f);
        const int row = rowb + r;
        if (ncol < 512) {
          const int h = ncol >> 6;
#pragma unroll
          for (int ni = 0; ni < 4; ++ni) {
            __fp16 hv = (__fp16)(acc[mi][ni][r] * sc2);
            qh[(row * Hh + h) * Dd + (ni << 4) + lane15] = *(unsigned short*)&hv;
          }
        } else {
          const int hkv = (ncol - 512) >> 6;
#pragma unroll
          for (int ni = 0; ni < 4; ++ni) {
            __fp16 hv = (__fp16)(acc[mi][ni][r] * sc2);
            kh[(row * HKV + hkv) * Dd + (ni << 4) + lane15] = *(unsigned short*)&hv;
          }
        }
      }
    }
  } else {
    // v: pack row-pairs (2j,2j+1) as h2 -> vhu[rowpair][hkv][d]
    const int hkv = (ncol - 768) >> 6;
#pragma unroll
    for (int mi = 0; mi < 4; ++mi) {
      const int rowb = m0 + mw + mi * 16 + ((lane >> 4) << 2);
#pragma unroll
      for (int r = 0; r < 4; r += 2) {
        const int rp = (rowb + r) >> 1;
#pragma unroll
        for (int ni = 0; ni < 4; ++ni) {
          unsigned u = h2u(__builtin_amdgcn_cvt_pkrtz(acc[mi][ni][r], acc[mi][ni][r + 1]));
          vhu[(rp * HKV + hkv) * Dd + (ni << 4) + lane15] = u;
        }
      }
    }
  }
}

// ---------------- Proj MFMA GEMM v2: 128x128 tile ----------------
__global__ __launch_bounds__(256) void proj_mfma(
    const unsigned short* __restrict__ yb, const unsigned short* __restrict__ Wt,
    float* __restrict__ out) {
  __shared__ unsigned short As[128][64];
  __shared__ unsigned short Bs[128][64];
  const int m0 = blockIdx.x * 128;
  const int n0 = blockIdx.y * 128;
  const int t = threadIdx.x;
  const int w = t >> 6, lane = t & 63;
  const int mw = (w >> 1) << 6;
  const int nw = (w & 1) << 6;
  const int srow = t >> 1, scol = (t & 1) << 5;
  float4v acc[4][4];
#pragma unroll
  for (int mi = 0; mi < 4; ++mi)
#pragma unroll
    for (int ni = 0; ni < 4; ++ni) acc[mi][ni] = (float4v){0, 0, 0, 0};

  for (int k0 = 0; k0 < 512; k0 += 64) {
    uint4 a[4], b[4];
    const uint4* ap = (const uint4*)&yb[(m0 + srow) * 512 + k0 + scol];
    const uint4* bp = (const uint4*)&Wt[(n0 + srow) * 512 + k0 + scol];
#pragma unroll
    for (int c = 0; c < 4; ++c) { a[c] = ap[c]; b[c] = bp[c]; }
    __syncthreads();
#pragma unroll
    for (int c = 0; c < 4; ++c) {
      ((uint4*)&As[srow][scol])[c] = a[c];
      ((uint4*)&Bs[srow][scol])[c] = b[c];
    }
    __syncthreads();
    const int lm = lane & 15;
    const int kq = (lane >> 4) << 3;
#pragma unroll
    for (int kh2 = 0; kh2 < 2; ++kh2) {
      short8 aF[4], bF[4];
#pragma unroll
      for (int mi = 0; mi < 4; ++mi)
        aF[mi] = *(short8*)&As[mw + mi * 16 + lm][kq + kh2 * 32];
#pragma unroll
      for (int ni = 0; ni < 4; ++ni)
        bF[ni] = *(short8*)&Bs[nw + ni * 16 + lm][kq + kh2 * 32];
#pragma unroll
      for (int mi = 0; mi < 4; ++mi)
#pragma unroll
        for (int ni = 0; ni < 4; ++ni)
          acc[mi][ni] = __builtin_amdgcn_mfma_f32_16x16x32_bf16(
              aF[mi], bF[ni], acc[mi][ni], 0, 0, 0);
    }
  }
  const int lane15 = lane & 15;
#pragma unroll
  for (int mi = 0; mi < 4; ++mi) {
    const int rowb = m0 + mw + mi * 16 + ((lane >> 4) << 2);
#pragma unroll
    for (int ni = 0; ni < 4; ++ni) {
      const int col = n0 + nw + (ni << 4) + lane15;
#pragma unroll
      for (int r = 0; r < 4; ++r)
        out[(rowb + r) * 512 + col] = acc[mi][ni][r];
    }
  }
}

// ---------------- Pwh[h][delta+511][d] table (fp16) ----------------
__global__ __launch_bounds__(256) void build_pw(const float* __restrict__ P,
                                                const float* __restrict__ sigma,
                                                unsigned short* __restrict__ Pwh) {
  int idx = blockIdx.x * blockDim.x + threadIdx.x;
  if (idx >= Hh * 1023 * 64) return;
  int d = idx & 63;
  int rem = idx >> 6;
  int dd = rem % 1023;
  int h = rem / 1023;
  float s = fabsf(sigma[h]) + 1e-6f;
  float delta = (float)(dd - 511);
  float dt = 128.0f * tanhf(delta / s) + 128.0f;
  float lo = floorf(dt);
  int ilo = (int)lo;
  float frac = dt - lo;
  ilo = max(0, min(ilo, 256));
  int ihi = min(ilo + 1, 256);
  const float* Pb = P + h * 257 * 64;
  float val = (1.0f - frac) * Pb[ilo * 64 + d] + frac * Pb[ihi * 64 + d];
  __fp16 hv = (__fp16)val;
  Pwh[idx] = *(unsigned short*)&hv;
}

// ---------------- Attention v8: fixed-shift softmax, q/K off the LDS pipe ----------------
__global__ __launch_bounds__(256) void attn(
    const unsigned short* __restrict__ qh, const unsigned short* __restrict__ kh,
    const unsigned* __restrict__ vhu, const unsigned short* __restrict__ Pwh,
    unsigned short* __restrict__ yb) {
  __shared__ __fp16 PwS[96][72];
  __shared__ __fp16 pS[4][32][16];

  const int t = threadIdx.x;
  const int lane = t & 63;
  const int wu = __builtin_amdgcn_readfirstlane(t >> 6);  // uniform wave id
  const int bh = blockIdx.x;
  const int b = bh >> 3;
  const int h = bh & 7;
  const int hkv = h >> 1;
  const int i0 = 480 - blockIdx.y * 32;  // heavy blocks first

  float l_lane[8], o_run[8];
#pragma unroll
  for (int r = 0; r < 8; ++r) { l_lane[r] = 0.0f; o_run[r] = 0.0f; }

  const int prow = (wu << 3) + 63 - lane;
  const int i_base = i0 + (wu << 3);
  const unsigned short* qbase = &qh[((b * Tt + i_base) * Hh + h) * Dd];

  for (int jt0 = 0; jt0 <= i0 + 31; jt0 += 64) {
    __syncthreads();
    {
      int jr = t >> 2, dc = (t & 3) << 4;
      const int pb0 = h * 1023 + (i0 - jt0) + 448;
      const unsigned short* pwp = &Pwh[(pb0 + jr) * 64 + dc];
      *(uint4*)&PwS[jr][dc]     = *(const uint4*)&pwp[0];
      *(uint4*)&PwS[jr][dc + 8] = *(const uint4*)&pwp[8];
      int pr2 = 64 + (t >> 3), dc2 = (t & 7) << 3;
      if (pr2 < 95)
        *(uint4*)&PwS[pr2][dc2] = *(const uint4*)&Pwh[(pb0 + pr2) * 64 + dc2];
    }
    uint4 kr[8];
    {
      const uint4* kp = (const uint4*)&kh[((b * Tt + jt0 + lane) * HKV + hkv) * Dd];
#pragma unroll
      for (int c = 0; c < 8; ++c) kr[c] = kp[c];
    }
    __syncthreads();

    const int j = jt0 + lane;
    float pv8[8];
#pragma unroll
    for (int r = 0; r < 8; ++r) {
      const uint4* qp = (const uint4*)&qbase[r * (Hh * Dd)];  // wave-uniform
      float sr = 0.0f;
#pragma unroll
      for (int ch = 0; ch < 8; ++ch) {
        uint4 qu = qp[ch];
        uint4 pu = *(uint4*)&PwS[prow + r][ch << 3];
        sr = fdot2(u2h(qu.x) * u2h(pu.x), u2h(kr[ch].x), sr);
        sr = fdot2(u2h(qu.y) * u2h(pu.y), u2h(kr[ch].y), sr);
        sr = fdot2(u2h(qu.z) * u2h(pu.z), u2h(kr[ch].z), sr);
        sr = fdot2(u2h(qu.w) * u2h(pu.w), u2h(kr[ch].w), sr);
      }
      float sv = (j <= i_base + r) ? sr * 0.125f : -1e30f;
      float p = __expf(sv - 6.0f);   // fixed shift: exact softmax, no reduce
      l_lane[r] += p;
      pv8[r] = p;
    }
    {
      unsigned u[8];
#pragma unroll
      for (int r = 0; r < 8; ++r) {
        float other = __shfl_xor(pv8[r], 1, 64);
        u[r] = h2u(__builtin_amdgcn_cvt_pkrtz(pv8[r], other));
      }
      if (!(lane & 1)) {
        *(uint4*)&pS[wu][lane >> 1][0] = *(uint4*)&u[0];
        *(uint4*)&pS[wu][lane >> 1][8] = *(uint4*)&u[4];
      }
    }

    const unsigned* vp = &vhu[(((b * Tt + jt0) >> 1) * HKV + hkv) * Dd + lane];
#pragma unroll 4
    for (int j2 = 0; j2 < 32; ++j2) {
      uint4 p0 = *(uint4*)&pS[wu][j2][0];
      uint4 p1 = *(uint4*)&pS[wu][j2][8];
      h2 vv = u2h(vp[j2 * (HKV * Dd)]);
      o_run[0] = fdot2(u2h(p0.x), vv, o_run[0]);
      o_run[1] = fdot2(u2h(p0.y), vv, o_run[1]);
      o_run[2] = fdot2(u2h(p0.z), vv, o_run[2]);
      o_run[3] = fdot2(u2h(p0.w), vv, o_run[3]);
      o_run[4] = fdot2(u2h(p1.x), vv, o_run[4]);
      o_run[5] = fdot2(u2h(p1.y), vv, o_run[5]);
      o_run[6] = fdot2(u2h(p1.z), vv, o_run[6]);
      o_run[7] = fdot2(u2h(p1.w), vv, o_run[7]);
    }
  }
#pragma unroll
  for (int r = 0; r < 8; ++r) {
    float l = wave_reduce_sum(l_lane[r]);
    const int i_r = i_base + r;
    __hip_bfloat16 hv = __float2bfloat16(o_run[r] / l);
    yb[((b * Tt + i_r) * Hh + h) * Dd + lane] = *(unsigned short*)&hv;
  }
}

extern "C" void kernel_launch(void* const* d_in, const int* in_sizes, int n_in,
                              void* d_out, int out_size, void* d_ws, size_t ws_size,
                              hipStream_t stream) {
  const float* x     = (const float*)d_in[0];
  const float* Wq    = (const float*)d_in[1];
  const float* Wk    = (const float*)d_in[2];
  const float* Wv    = (const float*)d_in[3];
  const float* Wproj = (const float*)d_in[4];
  const float* P     = (const float*)d_in[5];
  const float* sigma = (const float*)d_in[6];
  float* out = (float*)d_out;

  float* ws = (float*)d_ws;
  unsigned short* qh  = (unsigned short*)ws;                // 2,097,152 h = 1,048,576 f
  unsigned short* kh  = (unsigned short*)(ws + 1048576);    // 1,048,576 h = 524,288 f
  unsigned*       vhu = (unsigned*)(ws + 1572864);          // 524,288 u = 524,288 f
  unsigned short* Pwh = (unsigned short*)(ws + 2097152);    // 523,776 h -> 262,144 f
  unsigned short* xb  = (unsigned short*)(ws + 2359296);    // 2M bf16 = 1,048,576 f
  unsigned short* yb  = xb;                                 // alias: xb dead after qkv_mfma
  unsigned short* Wtq = (unsigned short*)(ws + 3407872);    // 524,288 h = 262,144 f
  unsigned short* Wtp = (unsigned short*)(ws + 3670016);    // 262,144 h = 131,072 f

  conv_x<<<dim3(1024), 256, 0, stream>>>(x, xb);
  conv_w<<<dim3(8, 24), 256, 0, stream>>>(Wq, Wk, Wv, Wproj, Wtq, Wtp);
  qkv_mfma<<<dim3(32, 8), 256, 0, stream>>>(xb, Wtq, qh, kh, vhu);
  build_pw<<<dim3(2046), 256, 0, stream>>>(P, sigma, Pwh);
  attn<<<dim3(64, 16), 256, 0, stream>>>(qh, kh, vhu, Pwh, yb);
  proj_mfma<<<dim3(32, 4), 256, 0, stream>>>(yb, Wtp, out);
}

// Round 11
// 183.712 us; speedup vs baseline: 1.0161x; 1.0161x over previous
//
#include <hip/hip_runtime.h>
#include <hip/hip_bf16.h>
#include <math.h>

#define Bb 8
#define Tt 512
#define Cc 512
#define Hh 8
#define HKV 4
#define Dd 64

typedef __attribute__((ext_vector_type(8))) short short8;
typedef __attribute__((ext_vector_type(4))) float float4v;
typedef __attribute__((ext_vector_type(2))) __fp16 h2;  // matches cvt_pkrtz return type

__device__ __forceinline__ h2 u2h(unsigned u) {
  union { unsigned u; h2 h; } x; x.u = u; return x.h;
}
__device__ __forceinline__ unsigned h2u(h2 h) {
  union { h2 h; unsigned u; } x; x.h = h; return x.u;
}
__device__ __forceinline__ float fdot2(h2 a, h2 b, float c) {
#if __has_builtin(__builtin_amdgcn_fdot2)
  return __builtin_amdgcn_fdot2(a, b, c, false);
#else
  return fmaf((float)a.x, (float)b.x, fmaf((float)a.y, (float)b.y, c));
#endif
}

__device__ __forceinline__ float wave_reduce_sum(float v) {
#pragma unroll
  for (int off = 32; off > 0; off >>= 1) v += __shfl_xor(v, off, 64);
  return v;
}
__device__ __forceinline__ unsigned pack_bf2(float a, float b) {
  __hip_bfloat162 h = __float22bfloat162_rn(make_float2(a, b));
  return *(unsigned*)&h;
}

// ---------------- fused prep: conv_x | conv_w | build_pw (by block range) ----------------
__global__ __launch_bounds__(256) void prep(
    const float* __restrict__ x, const float* __restrict__ Wq,
    const float* __restrict__ Wk, const float* __restrict__ Wv,
    const float* __restrict__ Wp, const float* __restrict__ P,
    const float* __restrict__ sigma,
    unsigned short* __restrict__ xb, unsigned short* __restrict__ Wtq,
    unsigned short* __restrict__ Wtp, unsigned short* __restrict__ Pwh) {
  const int bid = blockIdx.x;
  const int t = threadIdx.x;
  if (bid < 1024) {
    // ---- conv_x: fp32 -> bf16 ----
    int i = (bid * 256 + t) * 8;
    float4 f0 = *(const float4*)&x[i];
    float4 f1 = *(const float4*)&x[i + 4];
    unsigned u[4] = {pack_bf2(f0.x, f0.y), pack_bf2(f0.z, f0.w),
                     pack_bf2(f1.x, f1.y), pack_bf2(f1.z, f1.w)};
    *(uint4*)&xb[i] = *(uint4*)u;
  } else if (bid < 1216) {
    // ---- conv_w: transpose+convert Wt[n][k] bf16 ----
    __shared__ float Ts[64][65];
    const int bx = bid - 1024;
    const int k0 = (bx & 7) << 6;
    const int n0 = (bx >> 3) << 6;
    const float* src; int ld, nc0; unsigned short* dst; int ndst;
    if (n0 < 512)       { src = Wq; ld = 512; nc0 = n0;        dst = Wtq; ndst = n0; }
    else if (n0 < 768)  { src = Wk; ld = 256; nc0 = n0 - 512;  dst = Wtq; ndst = n0; }
    else if (n0 < 1024) { src = Wv; ld = 256; nc0 = n0 - 768;  dst = Wtq; ndst = n0; }
    else                { src = Wp; ld = 512; nc0 = n0 - 1024; dst = Wtp; ndst = n0 - 1024; }
    const int r = t >> 4, c4 = (t & 15) << 2;
#pragma unroll
    for (int rr = 0; rr < 4; ++rr) {
      int row = (rr << 4) + r;
      float4 f = *(const float4*)&src[(k0 + row) * ld + nc0 + c4];
      Ts[row][c4] = f.x; Ts[row][c4 + 1] = f.y;
      Ts[row][c4 + 2] = f.z; Ts[row][c4 + 3] = f.w;
    }
    __syncthreads();
#pragma unroll
    for (int rr = 0; rr < 4; ++rr) {
      int nr = (rr << 4) + r;
      unsigned u0 = pack_bf2(Ts[c4][nr], Ts[c4 + 1][nr]);
      unsigned u1 = pack_bf2(Ts[c4 + 2][nr], Ts[c4 + 3][nr]);
      *(uint2*)&dst[(ndst + nr) * 512 + k0 + c4] = make_uint2(u0, u1);
    }
  } else {
    // ---- build_pw: Pwh[h][delta+511][d] fp16 table ----
    int idx = (bid - 1216) * 256 + t;
    int d = idx & 63;
    int rem = idx >> 6;
    int dd = rem % 1023;
    int h = rem / 1023;
    float s = fabsf(sigma[h]) + 1e-6f;
    float delta = (float)(dd - 511);
    float dt = 128.0f * tanhf(delta / s) + 128.0f;
    float lo = floorf(dt);
    int ilo = (int)lo;
    float frac = dt - lo;
    ilo = max(0, min(ilo, 256));
    int ihi = min(ilo + 1, 256);
    const float* Pb = P + h * 257 * 64;
    float val = (1.0f - frac) * Pb[ilo * 64 + d] + frac * Pb[ihi * 64 + d];
    __fp16 hv = (__fp16)val;
    Pwh[idx] = *(unsigned short*)&hv;
  }
}

// ---------------- QKV MFMA GEMM: 128x128 tile, PADDED LDS (144B rows) ----------------
// Padding 64->72 elems: fragment-read start bank = 4*lm mod 32 -> 2-way (free);
// was 16-way conflicted at 128B rows (the round-10 regression).
__global__ __launch_bounds__(256) void qkv_mfma(
    const unsigned short* __restrict__ xb, const unsigned short* __restrict__ Wt,
    unsigned short* __restrict__ qh, unsigned short* __restrict__ kh,
    unsigned* __restrict__ vhu) {
  __shared__ unsigned short As[128][72];
  __shared__ unsigned short Bs[128][72];
  const int m0 = blockIdx.x * 128;
  const int n0 = blockIdx.y * 128;
  const int t = threadIdx.x;
  const int w = t >> 6, lane = t & 63;
  const int mw = (w >> 1) << 6;
  const int nw = (w & 1) << 6;
  const int srow = t >> 1, scol = (t & 1) << 5;  // 2 thr/row, 32 bf16 each
  float4v acc[4][4];
#pragma unroll
  for (int mi = 0; mi < 4; ++mi)
#pragma unroll
    for (int ni = 0; ni < 4; ++ni) acc[mi][ni] = (float4v){0, 0, 0, 0};

  for (int k0 = 0; k0 < 512; k0 += 64) {
    uint4 a[4], b[4];
    const uint4* ap = (const uint4*)&xb[(m0 + srow) * 512 + k0 + scol];
    const uint4* bp = (const uint4*)&Wt[(n0 + srow) * 512 + k0 + scol];
#pragma unroll
    for (int c = 0; c < 4; ++c) { a[c] = ap[c]; b[c] = bp[c]; }
    __syncthreads();
#pragma unroll
    for (int c = 0; c < 4; ++c) {
      ((uint4*)&As[srow][scol])[c] = a[c];
      ((uint4*)&Bs[srow][scol])[c] = b[c];
    }
    __syncthreads();
    const int lm = lane & 15;
    const int kq = (lane >> 4) << 3;
#pragma unroll
    for (int kh2 = 0; kh2 < 2; ++kh2) {
      short8 aF[4], bF[4];
#pragma unroll
      for (int mi = 0; mi < 4; ++mi)
        aF[mi] = *(short8*)&As[mw + mi * 16 + lm][kq + kh2 * 32];
#pragma unroll
      for (int ni = 0; ni < 4; ++ni)
        bF[ni] = *(short8*)&Bs[nw + ni * 16 + lm][kq + kh2 * 32];
#pragma unroll
      for (int mi = 0; mi < 4; ++mi)
#pragma unroll
        for (int ni = 0; ni < 4; ++ni)
          acc[mi][ni] = __builtin_amdgcn_mfma_f32_16x16x32_bf16(
              aF[mi], bF[ni], acc[mi][ni], 0, 0, 0);
    }
  }

  const int ncol = n0 + nw;        // head-aligned (0,64,...,960)
  const int lane15 = lane & 15;
  if (ncol < 768) {
    // q or k head: fused RMS-norm over the 64-wide head (= wave's n-span)
#pragma unroll
    for (int mi = 0; mi < 4; ++mi) {
      const int rowb = m0 + mw + mi * 16 + ((lane >> 4) << 2);
#pragma unroll
      for (int r = 0; r < 4; ++r) {
        float ss = 0.0f;
#pragma unroll
        for (int ni = 0; ni < 4; ++ni)
          ss = fmaf(acc[mi][ni][r], acc[mi][ni][r], ss);
#pragma unroll
        for (int off = 1; off < 16; off <<= 1) ss += __shfl_xor(ss, off, 64);
        float sc2 = 8.0f * rsqrtf(ss + 1e-6f);
        const int row = rowb + r;
        if (ncol < 512) {
          const int h = ncol >> 6;
#pragma unroll
          for (int ni = 0; ni < 4; ++ni) {
            __fp16 hv = (__fp16)(acc[mi][ni][r] * sc2);
            qh[(row * Hh + h) * Dd + (ni << 4) + lane15] = *(unsigned short*)&hv;
          }
        } else {
          const int hkv = (ncol - 512) >> 6;
#pragma unroll
          for (int ni = 0; ni < 4; ++ni) {
            __fp16 hv = (__fp16)(acc[mi][ni][r] * sc2);
            kh[(row * HKV + hkv) * Dd + (ni << 4) + lane15] = *(unsigned short*)&hv;
          }
        }
      }
    }
  } else {
    // v: pack row-pairs (2j,2j+1) as h2 -> vhu[rowpair][hkv][d]
    const int hkv = (ncol - 768) >> 6;
#pragma unroll
    for (int mi = 0; mi < 4; ++mi) {
      const int rowb = m0 + mw + mi * 16 + ((lane >> 4) << 2);
#pragma unroll
      for (int r = 0; r < 4; r += 2) {
        const int rp = (rowb + r) >> 1;
#pragma unroll
        for (int ni = 0; ni < 4; ++ni) {
          unsigned u = h2u(__builtin_amdgcn_cvt_pkrtz(acc[mi][ni][r], acc[mi][ni][r + 1]));
          vhu[(rp * HKV + hkv) * Dd + (ni << 4) + lane15] = u;
        }
      }
    }
  }
}

// ---------------- Proj MFMA GEMM: 128x128 tile, PADDED LDS ----------------
__global__ __launch_bounds__(256) void proj_mfma(
    const unsigned short* __restrict__ yb, const unsigned short* __restrict__ Wt,
    float* __restrict__ out) {
  __shared__ unsigned short As[128][72];
  __shared__ unsigned short Bs[128][72];
  const int m0 = blockIdx.x * 128;
  const int n0 = blockIdx.y * 128;
  const int t = threadIdx.x;
  const int w = t >> 6, lane = t & 63;
  const int mw = (w >> 1) << 6;
  const int nw = (w & 1) << 6;
  const int srow = t >> 1, scol = (t & 1) << 5;
  float4v acc[4][4];
#pragma unroll
  for (int mi = 0; mi < 4; ++mi)
#pragma unroll
    for (int ni = 0; ni < 4; ++ni) acc[mi][ni] = (float4v){0, 0, 0, 0};

  for (int k0 = 0; k0 < 512; k0 += 64) {
    uint4 a[4], b[4];
    const uint4* ap = (const uint4*)&yb[(m0 + srow) * 512 + k0 + scol];
    const uint4* bp = (const uint4*)&Wt[(n0 + srow) * 512 + k0 + scol];
#pragma unroll
    for (int c = 0; c < 4; ++c) { a[c] = ap[c]; b[c] = bp[c]; }
    __syncthreads();
#pragma unroll
    for (int c = 0; c < 4; ++c) {
      ((uint4*)&As[srow][scol])[c] = a[c];
      ((uint4*)&Bs[srow][scol])[c] = b[c];
    }
    __syncthreads();
    const int lm = lane & 15;
    const int kq = (lane >> 4) << 3;
#pragma unroll
    for (int kh2 = 0; kh2 < 2; ++kh2) {
      short8 aF[4], bF[4];
#pragma unroll
      for (int mi = 0; mi < 4; ++mi)
        aF[mi] = *(short8*)&As[mw + mi * 16 + lm][kq + kh2 * 32];
#pragma unroll
      for (int ni = 0; ni < 4; ++ni)
        bF[ni] = *(short8*)&Bs[nw + ni * 16 + lm][kq + kh2 * 32];
#pragma unroll
      for (int mi = 0; mi < 4; ++mi)
#pragma unroll
        for (int ni = 0; ni < 4; ++ni)
          acc[mi][ni] = __builtin_amdgcn_mfma_f32_16x16x32_bf16(
              aF[mi], bF[ni], acc[mi][ni], 0, 0, 0);
    }
  }
  const int lane15 = lane & 15;
#pragma unroll
  for (int mi = 0; mi < 4; ++mi) {
    const int rowb = m0 + mw + mi * 16 + ((lane >> 4) << 2);
#pragma unroll
    for (int ni = 0; ni < 4; ++ni) {
      const int col = n0 + nw + (ni << 4) + lane15;
#pragma unroll
      for (int r = 0; r < 4; ++r)
        out[(rowb + r) * 512 + col] = acc[mi][ni][r];
    }
  }
}

// ---------------- Attention v8: fixed-shift softmax, q/K off the LDS pipe ----------------
__global__ __launch_bounds__(256) void attn(
    const unsigned short* __restrict__ qh, const unsigned short* __restrict__ kh,
    const unsigned* __restrict__ vhu, const unsigned short* __restrict__ Pwh,
    unsigned short* __restrict__ yb) {
  __shared__ __fp16 PwS[96][72];
  __shared__ __fp16 pS[4][32][16];

  const int t = threadIdx.x;
  const int lane = t & 63;
  const int wu = __builtin_amdgcn_readfirstlane(t >> 6);  // uniform wave id
  const int bh = blockIdx.x;
  const int b = bh >> 3;
  const int h = bh & 7;
  const int hkv = h >> 1;
  const int i0 = 480 - blockIdx.y * 32;  // heavy blocks first

  float l_lane[8], o_run[8];
#pragma unroll
  for (int r = 0; r < 8; ++r) { l_lane[r] = 0.0f; o_run[r] = 0.0f; }

  const int prow = (wu << 3) + 63 - lane;
  const int i_base = i0 + (wu << 3);
  const unsigned short* qbase = &qh[((b * Tt + i_base) * Hh + h) * Dd];

  for (int jt0 = 0; jt0 <= i0 + 31; jt0 += 64) {
    __syncthreads();
    {
      int jr = t >> 2, dc = (t & 3) << 4;
      const int pb0 = h * 1023 + (i0 - jt0) + 448;
      const unsigned short* pwp = &Pwh[(pb0 + jr) * 64 + dc];
      *(uint4*)&PwS[jr][dc]     = *(const uint4*)&pwp[0];
      *(uint4*)&PwS[jr][dc + 8] = *(const uint4*)&pwp[8];
      int pr2 = 64 + (t >> 3), dc2 = (t & 7) << 3;
      if (pr2 < 95)
        *(uint4*)&PwS[pr2][dc2] = *(const uint4*)&Pwh[(pb0 + pr2) * 64 + dc2];
    }
    uint4 kr[8];
    {
      const uint4* kp = (const uint4*)&kh[((b * Tt + jt0 + lane) * HKV + hkv) * Dd];
#pragma unroll
      for (int c = 0; c < 8; ++c) kr[c] = kp[c];
    }
    __syncthreads();

    const int j = jt0 + lane;
    float pv8[8];
#pragma unroll
    for (int r = 0; r < 8; ++r) {
      const uint4* qp = (const uint4*)&qbase[r * (Hh * Dd)];  // wave-uniform
      float sr = 0.0f;
#pragma unroll
      for (int ch = 0; ch < 8; ++ch) {
        uint4 qu = qp[ch];
        uint4 pu = *(uint4*)&PwS[prow + r][ch << 3];
        sr = fdot2(u2h(qu.x) * u2h(pu.x), u2h(kr[ch].x), sr);
        sr = fdot2(u2h(qu.y) * u2h(pu.y), u2h(kr[ch].y), sr);
        sr = fdot2(u2h(qu.z) * u2h(pu.z), u2h(kr[ch].z), sr);
        sr = fdot2(u2h(qu.w) * u2h(pu.w), u2h(kr[ch].w), sr);
      }
      float sv = (j <= i_base + r) ? sr * 0.125f : -1e30f;
      float p = __expf(sv - 6.0f);   // fixed shift: exact softmax, no reduce
      l_lane[r] += p;
      pv8[r] = p;
    }
    {
      unsigned u[8];
#pragma unroll
      for (int r = 0; r < 8; ++r) {
        float other = __shfl_xor(pv8[r], 1, 64);
        u[r] = h2u(__builtin_amdgcn_cvt_pkrtz(pv8[r], other));
      }
      if (!(lane & 1)) {
        *(uint4*)&pS[wu][lane >> 1][0] = *(uint4*)&u[0];
        *(uint4*)&pS[wu][lane >> 1][8] = *(uint4*)&u[4];
      }
    }

    const unsigned* vp = &vhu[(((b * Tt + jt0) >> 1) * HKV + hkv) * Dd + lane];
#pragma unroll 4
    for (int j2 = 0; j2 < 32; ++j2) {
      uint4 p0 = *(uint4*)&pS[wu][j2][0];
      uint4 p1 = *(uint4*)&pS[wu][j2][8];
      h2 vv = u2h(vp[j2 * (HKV * Dd)]);
      o_run[0] = fdot2(u2h(p0.x), vv, o_run[0]);
      o_run[1] = fdot2(u2h(p0.y), vv, o_run[1]);
      o_run[2] = fdot2(u2h(p0.z), vv, o_run[2]);
      o_run[3] = fdot2(u2h(p0.w), vv, o_run[3]);
      o_run[4] = fdot2(u2h(p1.x), vv, o_run[4]);
      o_run[5] = fdot2(u2h(p1.y), vv, o_run[5]);
      o_run[6] = fdot2(u2h(p1.z), vv, o_run[6]);
      o_run[7] = fdot2(u2h(p1.w), vv, o_run[7]);
    }
  }
#pragma unroll
  for (int r = 0; r < 8; ++r) {
    float l = wave_reduce_sum(l_lane[r]);
    const int i_r = i_base + r;
    __hip_bfloat16 hv = __float2bfloat16(o_run[r] / l);
    yb[((b * Tt + i_r) * Hh + h) * Dd + lane] = *(unsigned short*)&hv;
  }
}

extern "C" void kernel_launch(void* const* d_in, const int* in_sizes, int n_in,
                              void* d_out, int out_size, void* d_ws, size_t ws_size,
                              hipStream_t stream) {
  const float* x     = (const float*)d_in[0];
  const float* Wq    = (const float*)d_in[1];
  const float* Wk    = (const float*)d_in[2];
  const float* Wv    = (const float*)d_in[3];
  const float* Wproj = (const float*)d_in[4];
  const float* P     = (const float*)d_in[5];
  const float* sigma = (const float*)d_in[6];
  float* out = (float*)d_out;

  float* ws = (float*)d_ws;
  unsigned short* qh  = (unsigned short*)ws;                // 2,097,152 h = 1,048,576 f
  unsigned short* kh  = (unsigned short*)(ws + 1048576);    // 1,048,576 h = 524,288 f
  unsigned*       vhu = (unsigned*)(ws + 1572864);          // 524,288 u = 524,288 f
  unsigned short* Pwh = (unsigned short*)(ws + 2097152);    // 523,776 h -> 262,144 f
  unsigned short* xb  = (unsigned short*)(ws + 2359296);    // 2M bf16 = 1,048,576 f
  unsigned short* yb  = xb;                                 // alias: xb dead after qkv_mfma
  unsigned short* Wtq = (unsigned short*)(ws + 3407872);    // 524,288 h = 262,144 f
  unsigned short* Wtp = (unsigned short*)(ws + 3670016);    // 262,144 h = 131,072 f

  prep<<<dim3(3262), 256, 0, stream>>>(x, Wq, Wk, Wv, Wproj, P, sigma,
                                       xb, Wtq, Wtp, Pwh);
  qkv_mfma<<<dim3(32, 8), 256, 0, stream>>>(xb, Wtq, qh, kh, vhu);
  attn<<<dim3(64, 16), 256, 0, stream>>>(qh, kh, vhu, Pwh, yb);
  proj_mfma<<<dim3(32, 4), 256, 0, stream>>>(yb, Wtp, out);
}

// Round 12
// 146.789 us; speedup vs baseline: 1.2717x; 1.2515x over previous
//
#include <hip/hip_runtime.h>
#include <hip/hip_bf16.h>
#include <math.h>

#define Bb 8
#define Tt 512
#define Cc 512
#define Hh 8
#define HKV 4
#define Dd 64

typedef __attribute__((ext_vector_type(8))) short short8;
typedef __attribute__((ext_vector_type(4))) float float4v;
typedef __attribute__((ext_vector_type(2))) __fp16 h2;  // matches cvt_pkrtz return type

__device__ __forceinline__ h2 u2h(unsigned u) {
  union { unsigned u; h2 h; } x; x.u = u; return x.h;
}
__device__ __forceinline__ unsigned h2u(h2 h) {
  union { h2 h; unsigned u; } x; x.h = h; return x.u;
}
__device__ __forceinline__ float fdot2(h2 a, h2 b, float c) {
#if __has_builtin(__builtin_amdgcn_fdot2)
  return __builtin_amdgcn_fdot2(a, b, c, false);
#else
  return fmaf((float)a.x, (float)b.x, fmaf((float)a.y, (float)b.y, c));
#endif
}

__device__ __forceinline__ float wave_reduce_sum(float v) {
#pragma unroll
  for (int off = 32; off > 0; off >>= 1) v += __shfl_xor(v, off, 64);
  return v;
}
__device__ __forceinline__ unsigned pack_bf2(float a, float b) {
  __hip_bfloat162 h = __float22bfloat162_rn(make_float2(a, b));
  return *(unsigned*)&h;
}

// ---------------- fused prep: conv_x | conv_w | build_pw (by block range) ----------------
__global__ __launch_bounds__(256) void prep(
    const float* __restrict__ x, const float* __restrict__ Wq,
    const float* __restrict__ Wk, const float* __restrict__ Wv,
    const float* __restrict__ Wp, const float* __restrict__ P,
    const float* __restrict__ sigma,
    unsigned short* __restrict__ xb, unsigned short* __restrict__ Wtq,
    unsigned short* __restrict__ Wtp, unsigned short* __restrict__ Pwh) {
  const int bid = blockIdx.x;
  const int t = threadIdx.x;
  if (bid < 1024) {
    // ---- conv_x: fp32 -> bf16 ----
    int i = (bid * 256 + t) * 8;
    float4 f0 = *(const float4*)&x[i];
    float4 f1 = *(const float4*)&x[i + 4];
    unsigned u[4] = {pack_bf2(f0.x, f0.y), pack_bf2(f0.z, f0.w),
                     pack_bf2(f1.x, f1.y), pack_bf2(f1.z, f1.w)};
    *(uint4*)&xb[i] = *(uint4*)u;
  } else if (bid < 1216) {
    // ---- conv_w: transpose+convert Wt[n][k] bf16 ----
    __shared__ float Ts[64][65];
    const int bx = bid - 1024;
    const int k0 = (bx & 7) << 6;
    const int n0 = (bx >> 3) << 6;
    const float* src; int ld, nc0; unsigned short* dst; int ndst;
    if (n0 < 512)       { src = Wq; ld = 512; nc0 = n0;        dst = Wtq; ndst = n0; }
    else if (n0 < 768)  { src = Wk; ld = 256; nc0 = n0 - 512;  dst = Wtq; ndst = n0; }
    else if (n0 < 1024) { src = Wv; ld = 256; nc0 = n0 - 768;  dst = Wtq; ndst = n0; }
    else                { src = Wp; ld = 512; nc0 = n0 - 1024; dst = Wtp; ndst = n0 - 1024; }
    const int r = t >> 4, c4 = (t & 15) << 2;
#pragma unroll
    for (int rr = 0; rr < 4; ++rr) {
      int row = (rr << 4) + r;
      float4 f = *(const float4*)&src[(k0 + row) * ld + nc0 + c4];
      Ts[row][c4] = f.x; Ts[row][c4 + 1] = f.y;
      Ts[row][c4 + 2] = f.z; Ts[row][c4 + 3] = f.w;
    }
    __syncthreads();
#pragma unroll
    for (int rr = 0; rr < 4; ++rr) {
      int nr = (rr << 4) + r;
      unsigned u0 = pack_bf2(Ts[c4][nr], Ts[c4 + 1][nr]);
      unsigned u1 = pack_bf2(Ts[c4 + 2][nr], Ts[c4 + 3][nr]);
      *(uint2*)&dst[(ndst + nr) * 512 + k0 + c4] = make_uint2(u0, u1);
    }
  } else {
    // ---- build_pw: Pwh[h][delta+511][d] fp16 table ----
    int idx = (bid - 1216) * 256 + t;
    int d = idx & 63;
    int rem = idx >> 6;
    int dd = rem % 1023;
    int h = rem / 1023;
    float s = fabsf(sigma[h]) + 1e-6f;
    float delta = (float)(dd - 511);
    float dt = 128.0f * tanhf(delta / s) + 128.0f;
    float lo = floorf(dt);
    int ilo = (int)lo;
    float frac = dt - lo;
    ilo = max(0, min(ilo, 256));
    int ihi = min(ilo + 1, 256);
    const float* Pb = P + h * 257 * 64;
    float val = (1.0f - frac) * Pb[ilo * 64 + d] + frac * Pb[ihi * 64 + d];
    __fp16 hv = (__fp16)val;
    Pwh[idx] = *(unsigned short*)&hv;
  }
}

// ---------------- QKV MFMA GEMM: 64x64 tile, PADDED LDS, 1024 blocks (4/CU) ----------------
// Round-9 structure (high occupancy) + 72-elem rows: fragment-read start bank
// = 4*(lane&15) -> conflict-free (was 16-way at 128B rows = ~36 us of stall).
__global__ __launch_bounds__(256) void qkv_mfma(
    const unsigned short* __restrict__ xb, const unsigned short* __restrict__ Wt,
    unsigned short* __restrict__ qh, unsigned short* __restrict__ kh,
    unsigned* __restrict__ vhu) {
  __shared__ unsigned short As[64][72];
  __shared__ unsigned short Bs[64][72];
  const int m0 = blockIdx.x * 64;
  const int n0 = blockIdx.y * 64;
  const int t = threadIdx.x;
  const int w = t >> 6, lane = t & 63;
  const int srow = t >> 2, sc = (t & 3) << 4;
  float4v acc[4] = {{0,0,0,0},{0,0,0,0},{0,0,0,0},{0,0,0,0}};
  for (int k0 = 0; k0 < 512; k0 += 64) {
    uint4 a0 = *(const uint4*)&xb[(m0 + srow) * 512 + k0 + sc];
    uint4 a1 = *(const uint4*)&xb[(m0 + srow) * 512 + k0 + sc + 8];
    uint4 b0 = *(const uint4*)&Wt[(n0 + srow) * 512 + k0 + sc];
    uint4 b1 = *(const uint4*)&Wt[(n0 + srow) * 512 + k0 + sc + 8];
    __syncthreads();
    *(uint4*)&As[srow][sc] = a0; *(uint4*)&As[srow][sc + 8] = a1;
    *(uint4*)&Bs[srow][sc] = b0; *(uint4*)&Bs[srow][sc + 8] = b1;
    __syncthreads();
    const int ml = (w << 4) + (lane & 15);
    const int kq = (lane >> 4) << 3;
    short8 aF0 = *(short8*)&As[ml][kq];
    short8 aF1 = *(short8*)&As[ml][kq + 32];
#pragma unroll
    for (int nt = 0; nt < 4; ++nt) {
      const int nl = (nt << 4) + (lane & 15);
      short8 bF0 = *(short8*)&Bs[nl][kq];
      short8 bF1 = *(short8*)&Bs[nl][kq + 32];
      acc[nt] = __builtin_amdgcn_mfma_f32_16x16x32_bf16(aF0, bF0, acc[nt], 0, 0, 0);
      acc[nt] = __builtin_amdgcn_mfma_f32_16x16x32_bf16(aF1, bF1, acc[nt], 0, 0, 0);
    }
  }
  const int lane15 = lane & 15;
  const int rowbase = m0 + (w << 4) + ((lane >> 4) << 2);
  if (n0 < 768) {
    // q or k head: fused RMS-norm over the 64-wide head (= this n-tile)
#pragma unroll
    for (int r = 0; r < 4; ++r) {
      float ss = 0.0f;
#pragma unroll
      for (int nt = 0; nt < 4; ++nt) ss = fmaf(acc[nt][r], acc[nt][r], ss);
#pragma unroll
      for (int off = 1; off < 16; off <<= 1) ss += __shfl_xor(ss, off, 64);
      float sc2 = 8.0f * rsqrtf(ss + 1e-6f);
      const int row = rowbase + r;
      if (n0 < 512) {
        const int h = n0 >> 6;
#pragma unroll
        for (int nt = 0; nt < 4; ++nt) {
          __fp16 hv = (__fp16)(acc[nt][r] * sc2);
          qh[(row * Hh + h) * Dd + (nt << 4) + lane15] = *(unsigned short*)&hv;
        }
      } else {
        const int hkv = (n0 - 512) >> 6;
#pragma unroll
        for (int nt = 0; nt < 4; ++nt) {
          __fp16 hv = (__fp16)(acc[nt][r] * sc2);
          kh[(row * HKV + hkv) * Dd + (nt << 4) + lane15] = *(unsigned short*)&hv;
        }
      }
    }
  } else {
    const int hkv = (n0 - 768) >> 6;
#pragma unroll
    for (int r = 0; r < 4; r += 2) {
      const int rp = (rowbase + r) >> 1;
#pragma unroll
      for (int nt = 0; nt < 4; ++nt) {
        unsigned u = h2u(__builtin_amdgcn_cvt_pkrtz(acc[nt][r], acc[nt][r + 1]));
        vhu[(rp * HKV + hkv) * Dd + (nt << 4) + lane15] = u;
      }
    }
  }
}

// ---------------- Proj MFMA GEMM: 64x64 tile, PADDED LDS, 512 blocks ----------------
__global__ __launch_bounds__(256) void proj_mfma(
    const unsigned short* __restrict__ yb, const unsigned short* __restrict__ Wt,
    float* __restrict__ out) {
  __shared__ unsigned short As[64][72];
  __shared__ unsigned short Bs[64][72];
  const int m0 = blockIdx.x * 64;
  const int n0 = blockIdx.y * 64;
  const int t = threadIdx.x;
  const int w = t >> 6, lane = t & 63;
  const int srow = t >> 2, sc = (t & 3) << 4;
  float4v acc[4] = {{0,0,0,0},{0,0,0,0},{0,0,0,0},{0,0,0,0}};
  for (int k0 = 0; k0 < 512; k0 += 64) {
    uint4 a0 = *(const uint4*)&yb[(m0 + srow) * 512 + k0 + sc];
    uint4 a1 = *(const uint4*)&yb[(m0 + srow) * 512 + k0 + sc + 8];
    uint4 b0 = *(const uint4*)&Wt[(n0 + srow) * 512 + k0 + sc];
    uint4 b1 = *(const uint4*)&Wt[(n0 + srow) * 512 + k0 + sc + 8];
    __syncthreads();
    *(uint4*)&As[srow][sc] = a0; *(uint4*)&As[srow][sc + 8] = a1;
    *(uint4*)&Bs[srow][sc] = b0; *(uint4*)&Bs[srow][sc + 8] = b1;
    __syncthreads();
    const int ml = (w << 4) + (lane & 15);
    const int kq = (lane >> 4) << 3;
    short8 aF0 = *(short8*)&As[ml][kq];
    short8 aF1 = *(short8*)&As[ml][kq + 32];
#pragma unroll
    for (int nt = 0; nt < 4; ++nt) {
      const int nl = (nt << 4) + (lane & 15);
      short8 bF0 = *(short8*)&Bs[nl][kq];
      short8 bF1 = *(short8*)&Bs[nl][kq + 32];
      acc[nt] = __builtin_amdgcn_mfma_f32_16x16x32_bf16(aF0, bF0, acc[nt], 0, 0, 0);
      acc[nt] = __builtin_amdgcn_mfma_f32_16x16x32_bf16(aF1, bF1, acc[nt], 0, 0, 0);
    }
  }
#pragma unroll
  for (int nt = 0; nt < 4; ++nt) {
    int col = n0 + (nt << 4) + (lane & 15);
#pragma unroll
    for (int r = 0; r < 4; ++r) {
      int row = m0 + (w << 4) + ((lane >> 4) << 2) + r;
      out[row * 512 + col] = acc[nt][r];
    }
  }
}

// ---------------- Attention v8: fixed-shift softmax, q/K off the LDS pipe ----------------
__global__ __launch_bounds__(256) void attn(
    const unsigned short* __restrict__ qh, const unsigned short* __restrict__ kh,
    const unsigned* __restrict__ vhu, const unsigned short* __restrict__ Pwh,
    unsigned short* __restrict__ yb) {
  __shared__ __fp16 PwS[96][72];
  __shared__ __fp16 pS[4][32][16];

  const int t = threadIdx.x;
  const int lane = t & 63;
  const int wu = __builtin_amdgcn_readfirstlane(t >> 6);  // uniform wave id
  const int bh = blockIdx.x;
  const int b = bh >> 3;
  const int h = bh & 7;
  const int hkv = h >> 1;
  const int i0 = 480 - blockIdx.y * 32;  // heavy blocks first

  float l_lane[8], o_run[8];
#pragma unroll
  for (int r = 0; r < 8; ++r) { l_lane[r] = 0.0f; o_run[r] = 0.0f; }

  const int prow = (wu << 3) + 63 - lane;
  const int i_base = i0 + (wu << 3);
  const unsigned short* qbase = &qh[((b * Tt + i_base) * Hh + h) * Dd];

  for (int jt0 = 0; jt0 <= i0 + 31; jt0 += 64) {
    __syncthreads();
    {
      int jr = t >> 2, dc = (t & 3) << 4;
      const int pb0 = h * 1023 + (i0 - jt0) + 448;
      const unsigned short* pwp = &Pwh[(pb0 + jr) * 64 + dc];
      *(uint4*)&PwS[jr][dc]     = *(const uint4*)&pwp[0];
      *(uint4*)&PwS[jr][dc + 8] = *(const uint4*)&pwp[8];
      int pr2 = 64 + (t >> 3), dc2 = (t & 7) << 3;
      if (pr2 < 95)
        *(uint4*)&PwS[pr2][dc2] = *(const uint4*)&Pwh[(pb0 + pr2) * 64 + dc2];
    }
    uint4 kr[8];
    {
      const uint4* kp = (const uint4*)&kh[((b * Tt + jt0 + lane) * HKV + hkv) * Dd];
#pragma unroll
      for (int c = 0; c < 8; ++c) kr[c] = kp[c];
    }
    __syncthreads();

    const int j = jt0 + lane;
    float pv8[8];
#pragma unroll
    for (int r = 0; r < 8; ++r) {
      const uint4* qp = (const uint4*)&qbase[r * (Hh * Dd)];  // wave-uniform
      float sr = 0.0f;
#pragma unroll
      for (int ch = 0; ch < 8; ++ch) {
        uint4 qu = qp[ch];
        uint4 pu = *(uint4*)&PwS[prow + r][ch << 3];
        sr = fdot2(u2h(qu.x) * u2h(pu.x), u2h(kr[ch].x), sr);
        sr = fdot2(u2h(qu.y) * u2h(pu.y), u2h(kr[ch].y), sr);
        sr = fdot2(u2h(qu.z) * u2h(pu.z), u2h(kr[ch].z), sr);
        sr = fdot2(u2h(qu.w) * u2h(pu.w), u2h(kr[ch].w), sr);
      }
      float sv = (j <= i_base + r) ? sr * 0.125f : -1e30f;
      float p = __expf(sv - 6.0f);   // fixed shift: exact softmax, no reduce
      l_lane[r] += p;
      pv8[r] = p;
    }
    {
      unsigned u[8];
#pragma unroll
      for (int r = 0; r < 8; ++r) {
        float other = __shfl_xor(pv8[r], 1, 64);
        u[r] = h2u(__builtin_amdgcn_cvt_pkrtz(pv8[r], other));
      }
      if (!(lane & 1)) {
        *(uint4*)&pS[wu][lane >> 1][0] = *(uint4*)&u[0];
        *(uint4*)&pS[wu][lane >> 1][8] = *(uint4*)&u[4];
      }
    }

    const unsigned* vp = &vhu[(((b * Tt + jt0) >> 1) * HKV + hkv) * Dd + lane];
#pragma unroll 4
    for (int j2 = 0; j2 < 32; ++j2) {
      uint4 p0 = *(uint4*)&pS[wu][j2][0];
      uint4 p1 = *(uint4*)&pS[wu][j2][8];
      h2 vv = u2h(vp[j2 * (HKV * Dd)]);
      o_run[0] = fdot2(u2h(p0.x), vv, o_run[0]);
      o_run[1] = fdot2(u2h(p0.y), vv, o_run[1]);
      o_run[2] = fdot2(u2h(p0.z), vv, o_run[2]);
      o_run[3] = fdot2(u2h(p0.w), vv, o_run[3]);
      o_run[4] = fdot2(u2h(p1.x), vv, o_run[4]);
      o_run[5] = fdot2(u2h(p1.y), vv, o_run[5]);
      o_run[6] = fdot2(u2h(p1.z), vv, o_run[6]);
      o_run[7] = fdot2(u2h(p1.w), vv, o_run[7]);
    }
  }
#pragma unroll
  for (int r = 0; r < 8; ++r) {
    float l = wave_reduce_sum(l_lane[r]);
    const int i_r = i_base + r;
    __hip_bfloat16 hv = __float2bfloat16(o_run[r] / l);
    yb[((b * Tt + i_r) * Hh + h) * Dd + lane] = *(unsigned short*)&hv;
  }
}

extern "C" void kernel_launch(void* const* d_in, const int* in_sizes, int n_in,
                              void* d_out, int out_size, void* d_ws, size_t ws_size,
                              hipStream_t stream) {
  const float* x     = (const float*)d_in[0];
  const float* Wq    = (const float*)d_in[1];
  const float* Wk    = (const float*)d_in[2];
  const float* Wv    = (const float*)d_in[3];
  const float* Wproj = (const float*)d_in[4];
  const float* P     = (const float*)d_in[5];
  const float* sigma = (const float*)d_in[6];
  float* out = (float*)d_out;

  float* ws = (float*)d_ws;
  unsigned short* qh  = (unsigned short*)ws;                // 2,097,152 h = 1,048,576 f
  unsigned short* kh  = (unsigned short*)(ws + 1048576);    // 1,048,576 h = 524,288 f
  unsigned*       vhu = (unsigned*)(ws + 1572864);          // 524,288 u = 524,288 f
  unsigned short* Pwh = (unsigned short*)(ws + 2097152);    // 523,776 h -> 262,144 f
  unsigned short* xb  = (unsigned short*)(ws + 2359296);    // 2M bf16 = 1,048,576 f
  unsigned short* yb  = xb;                                 // alias: xb dead after qkv_mfma
  unsigned short* Wtq = (unsigned short*)(ws + 3407872);    // 524,288 h = 262,144 f
  unsigned short* Wtp = (unsigned short*)(ws + 3670016);    // 262,144 h = 131,072 f

  prep<<<dim3(3262), 256, 0, stream>>>(x, Wq, Wk, Wv, Wproj, P, sigma,
                                       xb, Wtq, Wtp, Pwh);
  qkv_mfma<<<dim3(64, 16), 256, 0, stream>>>(xb, Wtq, qh, kh, vhu);
  attn<<<dim3(64, 16), 256, 0, stream>>>(qh, kh, vhu, Pwh, yb);
  proj_mfma<<<dim3(64, 8), 256, 0, stream>>>(yb, Wtp, out);
}

// Round 13
// 136.812 us; speedup vs baseline: 1.3645x; 1.0729x over previous
//
#include <hip/hip_runtime.h>
#include <hip/hip_bf16.h>
#include <math.h>

#define Bb 8
#define Tt 512
#define Cc 512
#define Hh 8
#define HKV 4
#define Dd 64

typedef __attribute__((ext_vector_type(8))) short short8;
typedef __attribute__((ext_vector_type(4))) float float4v;
typedef __attribute__((ext_vector_type(2))) __fp16 h2;   // matches cvt_pkrtz return
typedef __attribute__((ext_vector_type(8))) __fp16 half8; // f16 MFMA fragment

__device__ __forceinline__ h2 u2h(unsigned u) {
  union { unsigned u; h2 h; } x; x.u = u; return x.h;
}
__device__ __forceinline__ unsigned h2u(h2 h) {
  union { h2 h; unsigned u; } x; x.h = h; return x.u;
}
__device__ __forceinline__ float fdot2(h2 a, h2 b, float c) {
#if __has_builtin(__builtin_amdgcn_fdot2)
  return __builtin_amdgcn_fdot2(a, b, c, false);
#else
  return fmaf((float)a.x, (float)b.x, fmaf((float)a.y, (float)b.y, c));
#endif
}

__device__ __forceinline__ float wave_reduce_sum(float v) {
#pragma unroll
  for (int off = 32; off > 0; off >>= 1) v += __shfl_xor(v, off, 64);
  return v;
}
__device__ __forceinline__ unsigned pack_bf2(float a, float b) {
  __hip_bfloat162 h = __float22bfloat162_rn(make_float2(a, b));
  return *(unsigned*)&h;
}

// ---------------- fused prep: conv_x | conv_w | build_pw (by block range) ----------------
__global__ __launch_bounds__(256) void prep(
    const float* __restrict__ x, const float* __restrict__ Wq,
    const float* __restrict__ Wk, const float* __restrict__ Wv,
    const float* __restrict__ Wp, const float* __restrict__ P,
    const float* __restrict__ sigma,
    unsigned short* __restrict__ xb, unsigned short* __restrict__ Wtq,
    unsigned short* __restrict__ Wtp, unsigned short* __restrict__ Pwh) {
  const int bid = blockIdx.x;
  const int t = threadIdx.x;
  if (bid < 1024) {
    int i = (bid * 256 + t) * 8;
    float4 f0 = *(const float4*)&x[i];
    float4 f1 = *(const float4*)&x[i + 4];
    unsigned u[4] = {pack_bf2(f0.x, f0.y), pack_bf2(f0.z, f0.w),
                     pack_bf2(f1.x, f1.y), pack_bf2(f1.z, f1.w)};
    *(uint4*)&xb[i] = *(uint4*)u;
  } else if (bid < 1216) {
    __shared__ float Ts[64][65];
    const int bx = bid - 1024;
    const int k0 = (bx & 7) << 6;
    const int n0 = (bx >> 3) << 6;
    const float* src; int ld, nc0; unsigned short* dst; int ndst;
    if (n0 < 512)       { src = Wq; ld = 512; nc0 = n0;        dst = Wtq; ndst = n0; }
    else if (n0 < 768)  { src = Wk; ld = 256; nc0 = n0 - 512;  dst = Wtq; ndst = n0; }
    else if (n0 < 1024) { src = Wv; ld = 256; nc0 = n0 - 768;  dst = Wtq; ndst = n0; }
    else                { src = Wp; ld = 512; nc0 = n0 - 1024; dst = Wtp; ndst = n0 - 1024; }
    const int r = t >> 4, c4 = (t & 15) << 2;
#pragma unroll
    for (int rr = 0; rr < 4; ++rr) {
      int row = (rr << 4) + r;
      float4 f = *(const float4*)&src[(k0 + row) * ld + nc0 + c4];
      Ts[row][c4] = f.x; Ts[row][c4 + 1] = f.y;
      Ts[row][c4 + 2] = f.z; Ts[row][c4 + 3] = f.w;
    }
    __syncthreads();
#pragma unroll
    for (int rr = 0; rr < 4; ++rr) {
      int nr = (rr << 4) + r;
      unsigned u0 = pack_bf2(Ts[c4][nr], Ts[c4 + 1][nr]);
      unsigned u1 = pack_bf2(Ts[c4 + 2][nr], Ts[c4 + 3][nr]);
      *(uint2*)&dst[(ndst + nr) * 512 + k0 + c4] = make_uint2(u0, u1);
    }
  } else {
    int idx = (bid - 1216) * 256 + t;
    int d = idx & 63;
    int rem = idx >> 6;
    int dd = rem % 1023;
    int h = rem / 1023;
    float s = fabsf(sigma[h]) + 1e-6f;
    float delta = (float)(dd - 511);
    float dt = 128.0f * tanhf(delta / s) + 128.0f;
    float lo = floorf(dt);
    int ilo = (int)lo;
    float frac = dt - lo;
    ilo = max(0, min(ilo, 256));
    int ihi = min(ilo + 1, 256);
    const float* Pb = P + h * 257 * 64;
    float val = (1.0f - frac) * Pb[ilo * 64 + d] + frac * Pb[ihi * 64 + d];
    __fp16 hv = (__fp16)val;
    Pwh[idx] = *(unsigned short*)&hv;
  }
}

// ---------------- QKV MFMA GEMM: 64x64 tile, padded LDS; v emitted TRANSPOSED ----------------
__global__ __launch_bounds__(256) void qkv_mfma(
    const unsigned short* __restrict__ xb, const unsigned short* __restrict__ Wt,
    unsigned short* __restrict__ qh, unsigned short* __restrict__ kh,
    unsigned short* __restrict__ vT) {
  __shared__ unsigned short As[64][72];
  __shared__ unsigned short Bs[64][72];
  const int m0 = blockIdx.x * 64;
  const int n0 = blockIdx.y * 64;
  const int t = threadIdx.x;
  const int w = t >> 6, lane = t & 63;
  const int srow = t >> 2, sc = (t & 3) << 4;
  float4v acc[4] = {{0,0,0,0},{0,0,0,0},{0,0,0,0},{0,0,0,0}};
  for (int k0 = 0; k0 < 512; k0 += 64) {
    uint4 a0 = *(const uint4*)&xb[(m0 + srow) * 512 + k0 + sc];
    uint4 a1 = *(const uint4*)&xb[(m0 + srow) * 512 + k0 + sc + 8];
    uint4 b0 = *(const uint4*)&Wt[(n0 + srow) * 512 + k0 + sc];
    uint4 b1 = *(const uint4*)&Wt[(n0 + srow) * 512 + k0 + sc + 8];
    __syncthreads();
    *(uint4*)&As[srow][sc] = a0; *(uint4*)&As[srow][sc + 8] = a1;
    *(uint4*)&Bs[srow][sc] = b0; *(uint4*)&Bs[srow][sc + 8] = b1;
    __syncthreads();
    const int ml = (w << 4) + (lane & 15);
    const int kq = (lane >> 4) << 3;
    short8 aF0 = *(short8*)&As[ml][kq];
    short8 aF1 = *(short8*)&As[ml][kq + 32];
#pragma unroll
    for (int nt = 0; nt < 4; ++nt) {
      const int nl = (nt << 4) + (lane & 15);
      short8 bF0 = *(short8*)&Bs[nl][kq];
      short8 bF1 = *(short8*)&Bs[nl][kq + 32];
      acc[nt] = __builtin_amdgcn_mfma_f32_16x16x32_bf16(aF0, bF0, acc[nt], 0, 0, 0);
      acc[nt] = __builtin_amdgcn_mfma_f32_16x16x32_bf16(aF1, bF1, acc[nt], 0, 0, 0);
    }
  }
  const int lane15 = lane & 15;
  const int rowbase = m0 + (w << 4) + ((lane >> 4) << 2);
  if (n0 < 768) {
    // q or k head: fused RMS-norm over the 64-wide head (= this n-tile)
#pragma unroll
    for (int r = 0; r < 4; ++r) {
      float ss = 0.0f;
#pragma unroll
      for (int nt = 0; nt < 4; ++nt) ss = fmaf(acc[nt][r], acc[nt][r], ss);
#pragma unroll
      for (int off = 1; off < 16; off <<= 1) ss += __shfl_xor(ss, off, 64);
      float sc2 = 8.0f * rsqrtf(ss + 1e-6f);
      const int row = rowbase + r;
      if (n0 < 512) {
        const int h = n0 >> 6;
#pragma unroll
        for (int nt = 0; nt < 4; ++nt) {
          __fp16 hv = (__fp16)(acc[nt][r] * sc2);
          qh[(row * Hh + h) * Dd + (nt << 4) + lane15] = *(unsigned short*)&hv;
        }
      } else {
        const int hkv = (n0 - 512) >> 6;
#pragma unroll
        for (int nt = 0; nt < 4; ++nt) {
          __fp16 hv = (__fp16)(acc[nt][r] * sc2);
          kh[(row * HKV + hkv) * Dd + (nt << 4) + lane15] = *(unsigned short*)&hv;
        }
      }
    }
  } else {
    // v transposed: vT[((b*HKV+hkv)*64 + d)*512 + t], 4 consecutive t per store
    const int hkv = (n0 - 768) >> 6;
    const int bb = rowbase >> 9;       // batch (64-row tile is within one b)
    const int trow = rowbase & 511;
#pragma unroll
    for (int nt = 0; nt < 4; ++nt) {
      const int d = (nt << 4) + lane15;
      unsigned u0 = h2u(__builtin_amdgcn_cvt_pkrtz(acc[nt][0], acc[nt][1]));
      unsigned u1 = h2u(__builtin_amdgcn_cvt_pkrtz(acc[nt][2], acc[nt][3]));
      *(uint2*)&vT[((bb * HKV + hkv) * 64 + d) * 512 + trow] = make_uint2(u0, u1);
    }
  }
}

// ---------------- Proj MFMA GEMM: 64x64 tile, padded LDS ----------------
__global__ __launch_bounds__(256) void proj_mfma(
    const unsigned short* __restrict__ yb, const unsigned short* __restrict__ Wt,
    float* __restrict__ out) {
  __shared__ unsigned short As[64][72];
  __shared__ unsigned short Bs[64][72];
  const int m0 = blockIdx.x * 64;
  const int n0 = blockIdx.y * 64;
  const int t = threadIdx.x;
  const int w = t >> 6, lane = t & 63;
  const int srow = t >> 2, sc = (t & 3) << 4;
  float4v acc[4] = {{0,0,0,0},{0,0,0,0},{0,0,0,0},{0,0,0,0}};
  for (int k0 = 0; k0 < 512; k0 += 64) {
    uint4 a0 = *(const uint4*)&yb[(m0 + srow) * 512 + k0 + sc];
    uint4 a1 = *(const uint4*)&yb[(m0 + srow) * 512 + k0 + sc + 8];
    uint4 b0 = *(const uint4*)&Wt[(n0 + srow) * 512 + k0 + sc];
    uint4 b1 = *(const uint4*)&Wt[(n0 + srow) * 512 + k0 + sc + 8];
    __syncthreads();
    *(uint4*)&As[srow][sc] = a0; *(uint4*)&As[srow][sc + 8] = a1;
    *(uint4*)&Bs[srow][sc] = b0; *(uint4*)&Bs[srow][sc + 8] = b1;
    __syncthreads();
    const int ml = (w << 4) + (lane & 15);
    const int kq = (lane >> 4) << 3;
    short8 aF0 = *(short8*)&As[ml][kq];
    short8 aF1 = *(short8*)&As[ml][kq + 32];
#pragma unroll
    for (int nt = 0; nt < 4; ++nt) {
      const int nl = (nt << 4) + (lane & 15);
      short8 bF0 = *(short8*)&Bs[nl][kq];
      short8 bF1 = *(short8*)&Bs[nl][kq + 32];
      acc[nt] = __builtin_amdgcn_mfma_f32_16x16x32_bf16(aF0, bF0, acc[nt], 0, 0, 0);
      acc[nt] = __builtin_amdgcn_mfma_f32_16x16x32_bf16(aF1, bF1, acc[nt], 0, 0, 0);
    }
  }
#pragma unroll
  for (int nt = 0; nt < 4; ++nt) {
    int col = n0 + (nt << 4) + (lane & 15);
#pragma unroll
    for (int r = 0; r < 4; ++r) {
      int row = m0 + (w << 4) + ((lane >> 4) << 2) + r;
      out[row * 512 + col] = acc[nt][r];
    }
  }
}

// ---------------- Attention v9: fixed-shift softmax + MFMA PV ----------------
// Score (VALU, lane=j) writes P row-major to pS[32][72] fp16 (b16 stores, 2-way).
// PV: O[32x64] += P.V via mfma_f32_16x16x32_f16 — wave w owns i-tile (w&1),
// d-tiles 2(w>>1)..+1: 2 A-frag LDS reads + 4 B-frag global b128 (vT, VMEM pipe)
// + 4 MFMAs per j-tile. Replaces 64 pS LDS reads + 256 fdot2 VALU per wave-tile.
__global__ __launch_bounds__(256) void attn(
    const unsigned short* __restrict__ qh, const unsigned short* __restrict__ kh,
    const unsigned short* __restrict__ vT, const unsigned short* __restrict__ Pwh,
    unsigned short* __restrict__ yb) {
  __shared__ __fp16 PwS[96][72];
  __shared__ __fp16 pS[32][72];   // padded: A-frag start bank = 4*(i+joct) -> 2-way
  __shared__ float lS[32];

  const int t = threadIdx.x;
  const int lane = t & 63;
  const int wu = __builtin_amdgcn_readfirstlane(t >> 6);
  const int bh = blockIdx.x;
  const int b = bh >> 3;
  const int h = bh & 7;
  const int hkv = h >> 1;
  const int i0 = 480 - blockIdx.y * 32;  // heavy blocks first

  float l_lane[8];
#pragma unroll
  for (int r = 0; r < 8; ++r) l_lane[r] = 0.0f;
  float4v oacc[2] = {{0, 0, 0, 0}, {0, 0, 0, 0}};

  const int prow = (wu << 3) + 63 - lane;
  const int i_base = i0 + (wu << 3);
  const unsigned short* qbase = &qh[((b * Tt + i_base) * Hh + h) * Dd];

  // PV fragment roles
  const int i16 = (wu & 1) << 4;        // A-operand i-tile base row in pS
  const int dt0 = (wu >> 1) << 1;       // first of 2 d-tiles
  const int lm = lane & 15;
  const int kq = (lane >> 4) << 3;      // k (j) octet within 32-half
  const unsigned short* vTbase = &vT[((b * HKV + hkv) * 64) * 512];

  for (int jt0 = 0; jt0 <= i0 + 31; jt0 += 64) {
    __syncthreads();   // guards PwS restage + pS rewrite vs prior PV reads
    {
      int jr = t >> 2, dc = (t & 3) << 4;
      const int pb0 = h * 1023 + (i0 - jt0) + 448;
      const unsigned short* pwp = &Pwh[(pb0 + jr) * 64 + dc];
      *(uint4*)&PwS[jr][dc]     = *(const uint4*)&pwp[0];
      *(uint4*)&PwS[jr][dc + 8] = *(const uint4*)&pwp[8];
      int pr2 = 64 + (t >> 3), dc2 = (t & 7) << 3;
      if (pr2 < 95)
        *(uint4*)&PwS[pr2][dc2] = *(const uint4*)&Pwh[(pb0 + pr2) * 64 + dc2];
    }
    uint4 kr[8];
    {
      const uint4* kp = (const uint4*)&kh[((b * Tt + jt0 + lane) * HKV + hkv) * Dd];
#pragma unroll
      for (int c = 0; c < 8; ++c) kr[c] = kp[c];
    }
    __syncthreads();   // PwS ready

    // ---- score phase: lane = j; q broadcast from global, Pw from LDS, K regs ----
    const int j = jt0 + lane;
#pragma unroll
    for (int r = 0; r < 8; ++r) {
      const uint4* qp = (const uint4*)&qbase[r * (Hh * Dd)];  // wave-uniform
      float sr = 0.0f;
#pragma unroll
      for (int ch = 0; ch < 8; ++ch) {
        uint4 qu = qp[ch];
        uint4 pu = *(uint4*)&PwS[prow + r][ch << 3];
        sr = fdot2(u2h(qu.x) * u2h(pu.x), u2h(kr[ch].x), sr);
        sr = fdot2(u2h(qu.y) * u2h(pu.y), u2h(kr[ch].y), sr);
        sr = fdot2(u2h(qu.z) * u2h(pu.z), u2h(kr[ch].z), sr);
        sr = fdot2(u2h(qu.w) * u2h(pu.w), u2h(kr[ch].w), sr);
      }
      float sv = (j <= i_base + r) ? sr * 0.125f : -1e30f;
      float p = __expf(sv - 6.0f);   // fixed shift: exact softmax, no reduce
      l_lane[r] += p;
      pS[(wu << 3) + r][lane] = (__fp16)p;   // b16 store, 2-way banks
    }
    __syncthreads();   // pS ready for all waves

    // ---- PV phase: MFMA f16, A from pS, B from vT (global, L1/L2-hot) ----
    half8 a0 = *(half8*)&pS[i16 + lm][kq];
    half8 a1 = *(half8*)&pS[i16 + lm][kq + 32];
#pragma unroll
    for (int dd = 0; dd < 2; ++dd) {
      const unsigned short* vp = vTbase + (((dt0 + dd) << 4) + lm) * 512 + jt0 + kq;
      half8 b0 = *(const half8*)&vp[0];
      half8 b1 = *(const half8*)&vp[32];
      oacc[dd] = __builtin_amdgcn_mfma_f32_16x16x32_f16(a0, b0, oacc[dd], 0, 0, 0);
      oacc[dd] = __builtin_amdgcn_mfma_f32_16x16x32_f16(a1, b1, oacc[dd], 0, 0, 0);
    }
  }

  // final l reduction (once), shared via lS (score rows != C-layout rows)
#pragma unroll
  for (int r = 0; r < 8; ++r) {
    float lr = wave_reduce_sum(l_lane[r]);
    if (lane == r) lS[(wu << 3) + r] = lr;
  }
  __syncthreads();

  // epilogue: C layout — row = i16 + quad*4 + reg, col = d-tile*16 + lm
#pragma unroll
  for (int dd = 0; dd < 2; ++dd) {
    const int d = ((dt0 + dd) << 4) + lm;
#pragma unroll
    for (int r = 0; r < 4; ++r) {
      const int irow = i16 + ((lane >> 4) << 2) + r;
      const float val = oacc[dd][r] / lS[irow];
      __hip_bfloat16 hv = __float2bfloat16(val);
      yb[((b * Tt + i0 + irow) * Hh + h) * Dd + d] = *(unsigned short*)&hv;
    }
  }
}

extern "C" void kernel_launch(void* const* d_in, const int* in_sizes, int n_in,
                              void* d_out, int out_size, void* d_ws, size_t ws_size,
                              hipStream_t stream) {
  const float* x     = (const float*)d_in[0];
  const float* Wq    = (const float*)d_in[1];
  const float* Wk    = (const float*)d_in[2];
  const float* Wv    = (const float*)d_in[3];
  const float* Wproj = (const float*)d_in[4];
  const float* P     = (const float*)d_in[5];
  const float* sigma = (const float*)d_in[6];
  float* out = (float*)d_out;

  float* ws = (float*)d_ws;
  unsigned short* qh  = (unsigned short*)ws;                // 2,097,152 h = 1,048,576 f
  unsigned short* kh  = (unsigned short*)(ws + 1048576);    // 1,048,576 h = 524,288 f
  unsigned short* vT  = (unsigned short*)(ws + 1572864);    // 1,048,576 h = 524,288 f (transposed)
  unsigned short* Pwh = (unsigned short*)(ws + 2097152);    // 523,776 h -> 262,144 f
  unsigned short* xb  = (unsigned short*)(ws + 2359296);    // 2M bf16 = 1,048,576 f
  unsigned short* yb  = xb;                                 // alias: xb dead after qkv_mfma
  unsigned short* Wtq = (unsigned short*)(ws + 3407872);    // 524,288 h = 262,144 f
  unsigned short* Wtp = (unsigned short*)(ws + 3670016);    // 262,144 h = 131,072 f

  prep<<<dim3(3262), 256, 0, stream>>>(x, Wq, Wk, Wv, Wproj, P, sigma,
                                       xb, Wtq, Wtp, Pwh);
  qkv_mfma<<<dim3(64, 16), 256, 0, stream>>>(xb, Wtq, qh, kh, vT);
  attn<<<dim3(64, 16), 256, 0, stream>>>(qh, kh, vT, Pwh, yb);
  proj_mfma<<<dim3(64, 8), 256, 0, stream>>>(yb, Wtp, out);
}